// Round 8
// baseline (201.620 us; speedup 1.0000x reference)
//
#include <hip/hip_runtime.h>
#include <hip/hip_bf16.h>

#define T_LEN 28
#define EMB   28
#define HID   256
#define NOUT  10
#define BATCH 32768
#define SCALE 2.8853900817779268f   // 2/ln2 folded into W2A/W1A/bias so tanh uses exp2 directly

typedef _Float16 f16x8  __attribute__((ext_vector_type(8)));
typedef _Float16 f16x4  __attribute__((ext_vector_type(4)));
typedef float    f32x4  __attribute__((ext_vector_type(4)));
typedef float    f32x16 __attribute__((ext_vector_type(16)));

// A-operand fragments for v_mfma_f32_32x32x16_f16 (row = l&31, k = (l>>5)*8 + q):
// W2A: [jt(8)][kb(16)][l(64)][q(8)] -> A[j][k], j = jt*32+(l&31), k = kb*16+(l>>5)*8+q, scaled by SCALE
// W1A: [jt(8)][kb(2)][l(64)][q(8)]  -> A[j][e], e = kb*16+(l>>5)*8+q
//      e==28 carries SCALE*(b1+b2) (matched by x-slot 1.0), e>28 zero.
__global__ __launch_bounds__(256) void prep_kernel(
    const float* __restrict__ W1, const float* __restrict__ W2,
    const float* __restrict__ b1, const float* __restrict__ b2,
    _Float16* __restrict__ W2A, _Float16* __restrict__ W1A) {
    int idx = blockIdx.x * 256 + threadIdx.x;
    if (idx < 65536) {
        int q  = idx & 7;
        int lm = (idx >> 3) & 63;
        int kb = (idx >> 9) & 15;
        int jt = idx >> 13;
        int j  = jt * 32 + (lm & 31);
        int k  = kb * 16 + (lm >> 5) * 8 + q;
        W2A[idx] = (_Float16)(SCALE * W2[j * HID + k]);
    }
    if (idx < 8192) {
        int q  = idx & 7;
        int lm = (idx >> 3) & 63;
        int kb = (idx >> 9) & 1;
        int jt = idx >> 10;
        int j  = jt * 32 + (lm & 31);
        int e  = kb * 16 + (lm >> 5) * 8 + q;
        float v = (e < EMB) ? SCALE * W1[j * EMB + e]
                            : (e == EMB ? SCALE * (b1[j] + b2[j]) : 0.f);
        W1A[idx] = (_Float16)v;
    }
}

// Block = 64 batch rows = two 32-row streams (A: 0-31, B: 32-63), 512 thr = 8 waves.
// Wave wv owns 32 feature cols (j-tile jt = wv) -> w2f only 64 regs, acc 16/stream.
// Dual-stream pipeline per step t:
//   phase1: accA(t) = W2*hA(t-1) + W1*xA(t)  || tanh_B(t-1) -> hB ; barrier
//   phase2: accB(t) = W2*hB(t-1) + W1*xB(t)  || tanh_A(t)   -> hA ; barrier
// tanh of one stream overlaps the 16-MFMA chain of the other INSIDE each wave (ILP).
// h LDS k-major chunks: chunk c (k=c*8..c*8+7) at (c*32+row)*16; B-frag read =
// base + l*16 + kb*1024 (linear 16B/lane, conflict-free).
__global__ __launch_bounds__(512, 2) void rnn_kernel(
    const float* __restrict__ seq,
    const _Float16* __restrict__ W2A,
    const _Float16* __restrict__ W1A,
    const float* __restrict__ W3,
    const float* __restrict__ b3,
    float* __restrict__ out)
{
    __shared__ __align__(16) char hls[2][16384];   // [0]=hA, [1]=hB

    const int tid = threadIdx.x;
    const int l   = tid & 63;
    const int wv  = tid >> 6;          // 0..7 = j-tile
    const int lo  = l & 31;
    const int hi  = l >> 5;
    const int r0  = blockIdx.x * 64;

    // W2/W1 A-fragments: single j-tile jt=wv, 16 k-windows -> 64 regs (+8 for w1f)
    f16x8 w2f[16];
#pragma unroll
    for (int kb = 0; kb < 16; ++kb)
        w2f[kb] = *(const f16x8*)(W2A + (((wv * 16 + kb) * 64 + l) * 8));
    f16x8 w1f[2];
#pragma unroll
    for (int kb = 0; kb < 2; ++kb)
        w1f[kb] = *(const f16x8*)(W1A + (((wv * 2 + kb) * 64 + l) * 8));

    // LDS write base: C reg-quad q holds rows j = wv*32 + q*8 + 4*hi + (0..3)
    // -> chunk c = wv*4 + q, byte (c*32+lo)*16 + hi*8 = wbase + q*512
    const int wbase = (wv * 128 + lo) * 16 + hi * 8;

    const float* rowA = seq + (size_t)(r0 + lo) * (T_LEN * EMB);
    const float* rowB = seq + (size_t)(r0 + 32 + lo) * (T_LEN * EMB);

    auto load_raw = [&](const float* rowp, int t, f32x4 r[4]) {
        const float* sp  = rowp + t * EMB + hi * 8;
        const float* sp2 = rowp + t * EMB + 16 + hi * 8;
        r[0] = *(const f32x4*)sp;
        r[1] = *(const f32x4*)(sp + 4);
        r[2] = *(const f32x4*)sp2;                        // hi=1: e 24..27
        if (hi == 0) r[3] = *(const f32x4*)(sp2 + 4);     // e 20..23
        else         r[3] = (f32x4){1.f, 0.f, 0.f, 0.f};  // e28 bias slot
    };
    auto cvt_x = [&](const f32x4 r[4], f16x8& x0, f16x8& x1) {
#pragma unroll
        for (int q = 0; q < 4; ++q) {
            x0[q] = (_Float16)r[0][q]; x0[4 + q] = (_Float16)r[1][q];
            x1[q] = (_Float16)r[2][q]; x1[4 + q] = (_Float16)r[3][q];
        }
    };
    auto tanh_store = [&](const f32x16& acc, char* buf) {
#pragma unroll
        for (int q = 0; q < 4; ++q) {
            f16x4 hv;
#pragma unroll
            for (int r = 0; r < 4; ++r) {
                float e  = __builtin_amdgcn_exp2f(acc[q * 4 + r]);   // pre-scaled: e^(2y)
                float rc = __builtin_amdgcn_rcpf(e + 1.f);
                hv[r] = (_Float16)__builtin_fmaf(-2.f, rc, 1.f);
            }
            *(f16x4*)(buf + wbase + q * 512) = hv;
        }
    };

    const f32x16 z = (f32x16)(0.f);
    f32x16 accA, accB;
    f32x4 ra[4], rb[4];

    // ---- prologue t=0: x-only for both streams; hA(0) written ----
    {
        load_raw(rowA, 0, ra);
        load_raw(rowB, 0, rb);
        f16x8 xa0, xa1, xb0, xb1;
        cvt_x(ra, xa0, xa1);
        cvt_x(rb, xb0, xb1);
        load_raw(rowA, 1, ra);           // prefetch xA(1)
        accA = __builtin_amdgcn_mfma_f32_32x32x16_f16(w1f[0], xa0, z, 0, 0, 0);
        accA = __builtin_amdgcn_mfma_f32_32x32x16_f16(w1f[1], xa1, accA, 0, 0, 0);
        accB = __builtin_amdgcn_mfma_f32_32x32x16_f16(w1f[0], xb0, z, 0, 0, 0);
        accB = __builtin_amdgcn_mfma_f32_32x32x16_f16(w1f[1], xb1, accB, 0, 0, 0);
        tanh_store(accA, hls[0]);
    }
    __syncthreads();   // hA(0) visible

    for (int t = 1; t < T_LEN; ++t) {
        // ---- phase 1: accA(t) = W2*hA(t-1) + W1*xA(t)  ||  tanh_B(t-1) -> hB ----
        {
            f16x8 xa0, xa1;
            cvt_x(ra, xa0, xa1);
            load_raw(rowB, t, rb);                      // xB(t), consumed in phase 2
            const char* rp = hls[0] + l * 16;
#pragma unroll
            for (int kb = 0; kb < 16; ++kb) {
                f16x8 hB = *(const f16x8*)(rp + kb * 1024);
                accA = __builtin_amdgcn_mfma_f32_32x32x16_f16(
                           w2f[kb], hB, (kb == 0) ? z : accA, 0, 0, 0);
            }
            tanh_store(accB, hls[1]);                   // overlaps accA MFMA chain
            accA = __builtin_amdgcn_mfma_f32_32x32x16_f16(w1f[0], xa0, accA, 0, 0, 0);
            accA = __builtin_amdgcn_mfma_f32_32x32x16_f16(w1f[1], xa1, accA, 0, 0, 0);
        }
        __syncthreads();   // hB(t-1) visible; hA reads done

        // ---- phase 2: accB(t) = W2*hB(t-1) + W1*xB(t)  ||  tanh_A(t) -> hA ----
        {
            f16x8 xb0, xb1;
            cvt_x(rb, xb0, xb1);
            load_raw(rowA, (t < T_LEN - 1) ? t + 1 : t, ra);   // xA(t+1)
            const char* rp = hls[1] + l * 16;
#pragma unroll
            for (int kb = 0; kb < 16; ++kb) {
                f16x8 hB = *(const f16x8*)(rp + kb * 1024);
                accB = __builtin_amdgcn_mfma_f32_32x32x16_f16(
                           w2f[kb], hB, (kb == 0) ? z : accB, 0, 0, 0);
            }
            tanh_store(accA, hls[0]);                   // overlaps accB MFMA chain
            accB = __builtin_amdgcn_mfma_f32_32x32x16_f16(w1f[0], xb0, accB, 0, 0, 0);
            accB = __builtin_amdgcn_mfma_f32_32x32x16_f16(w1f[1], xb1, accB, 0, 0, 0);
        }
        __syncthreads();   // hA(t) visible; hB reads done
    }

    // ---- epilogue: tanh_B(T-1) -> hB ----
    tanh_store(accB, hls[1]);
    __syncthreads();

    // ---- head: out = h @ W3^T + b3 over 64 rows ----
    for (int idx = tid; idx < 64 * NOUT; idx += 512) {
        int i = idx / NOUT;
        int o = idx - i * NOUT;
        const char* hb = hls[i >> 5];
        int row = i & 31;
        float s = b3[o];
#pragma unroll
        for (int c = 0; c < 32; ++c) {
            f16x8 hv  = *(const f16x8*)(hb + c * 512 + row * 16);
            f32x4 w0  = *(const f32x4*)(W3 + o * HID + c * 8);
            f32x4 w1v = *(const f32x4*)(W3 + o * HID + c * 8 + 4);
#pragma unroll
            for (int q = 0; q < 4; ++q)
                s += (float)hv[q] * w0[q] + (float)hv[4 + q] * w1v[q];
        }
        out[(size_t)(r0 + i) * NOUT + o] = s;
    }
}

extern "C" void kernel_launch(void* const* d_in, const int* in_sizes, int n_in,
                              void* d_out, int out_size, void* d_ws, size_t ws_size,
                              hipStream_t stream) {
    const float* seq = (const float*)d_in[0];
    const float* W1  = (const float*)d_in[1];
    const float* b1  = (const float*)d_in[2];
    const float* W2  = (const float*)d_in[3];
    const float* b2  = (const float*)d_in[4];
    const float* W3  = (const float*)d_in[5];
    const float* b3  = (const float*)d_in[6];
    float* outp = (float*)d_out;

    _Float16* W2A = (_Float16*)d_ws;
    _Float16* W1A = (_Float16*)((char*)d_ws + 65536 * sizeof(_Float16));

    prep_kernel<<<256, 256, 0, stream>>>(W1, W2, b1, b2, W2A, W1A);
    rnn_kernel<<<BATCH / 64, 512, 0, stream>>>(seq, W2A, W1A, W3, b3, outp);
}